// Round 1
// baseline (732.585 us; speedup 1.0000x reference)
//
#include <hip/hip_runtime.h>
#include <hip/hip_bf16.h>

// Problem: B=32, S=4096, D=512.
// out = [att_weights (32,4096) fp32 | hidden_output (32,512) fp32]

typedef __attribute__((ext_vector_type(8))) short bf16x8;
typedef __attribute__((ext_vector_type(4))) float f32x4;

#define BM 128
#define BN 128
#define BKK 32
#define LDA 40   // bf16 elems per LDS row: 32 + 8 pad (80 B, 16B-aligned rows)

static __device__ __forceinline__ short f2bf(float f) {
    union { float f; unsigned u; } v; v.f = f;
    unsigned r = v.u + 0x7fffu + ((v.u >> 16) & 1u);   // RNE
    return (short)(r >> 16);
}

static __device__ __forceinline__ float fast_tanh(float x) {
    // tanh(x) = 1 - 2/(exp(2x)+1); exp2-based, saturates correctly at +-inf
    float ex = exp2f(x * 2.8853900817779268f);
    return 1.0f - 2.0f / (ex + 1.0f);
}

// ---- t[b,h] = sum_d targ[b,d] * W[h, d]  (Wt = first 512 cols of W) ----
__global__ void t_kernel(const float* __restrict__ targ,
                         const float* __restrict__ W,
                         float* __restrict__ t) {
    __shared__ float tg[512];
    const int b = blockIdx.x;
    const int tid = threadIdx.x;            // 256
    tg[tid]       = targ[b * 512 + tid];
    tg[tid + 256] = targ[b * 512 + tid + 256];
    __syncthreads();
    const int lane = tid & 63, wave = tid >> 6;
    for (int h = wave; h < 512; h += 4) {
        const float* wr = W + (long)h * 1024;      // row h, cols 0..511
        float s = 0.f;
        #pragma unroll
        for (int i = 0; i < 2; i++) {
            const int d = lane * 4 + i * 256;
            float4 wv = *(const float4*)(wr + d);
            s += wv.x * tg[d] + wv.y * tg[d + 1] + wv.z * tg[d + 2] + wv.w * tg[d + 3];
        }
        s += __shfl_xor(s, 1);  s += __shfl_xor(s, 2);  s += __shfl_xor(s, 4);
        s += __shfl_xor(s, 8);  s += __shfl_xor(s, 16); s += __shfl_xor(s, 32);
        if (lane == 0) t[b * 512 + h] = s;
    }
}

// ---- e[m] += sum_h tanh(src@Ws^T + t)[m,h] * V[h], MFMA bf16 GEMM ----
// A = src (M=131072, K=512) row-major fp32; Bmat[h,k] = W[h, 512+k].
// grid (4 h-tiles, 1024 m-tiles), block 256 = 4 waves (2x2), 64x64 per wave.
__global__ __launch_bounds__(256, 2)
void gemm_e_kernel(const float* __restrict__ src,
                   const float* __restrict__ W,
                   const float* __restrict__ t,
                   const float* __restrict__ V,
                   float* __restrict__ e) {
    __shared__ __align__(16) short As[BM * LDA];
    __shared__ __align__(16) short Bs[BN * LDA];

    const int tid = threadIdx.x;
    const int h0 = blockIdx.x * BN;
    const long m0 = (long)blockIdx.y * BM;
    const int b = (int)(m0 >> 12);                 // m / 4096

    const int lane = tid & 63;
    const int wave = tid >> 6;
    const int wm = wave & 1, wn = wave >> 1;
    const int lr = lane & 15, quad = lane >> 4;

    f32x4 acc[4][4];
    #pragma unroll
    for (int i = 0; i < 4; i++)
        #pragma unroll
        for (int j = 0; j < 4; j++)
            acc[i][j] = (f32x4){0.f, 0.f, 0.f, 0.f};

    for (int kt = 0; kt < 512; kt += BKK) {
        __syncthreads();
        // stage A and B tiles: 128 rows x 32 k fp32 -> bf16 LDS
        #pragma unroll
        for (int i = 0; i < 4; i++) {
            const int j = tid + 256 * i;           // 0..1023
            const int row = j >> 3, c4 = j & 7;
            float4 va = *(const float4*)(src + (m0 + row) * 512 + kt + c4 * 4);
            float4 vb = *(const float4*)(W + (long)(h0 + row) * 1024 + 512 + kt + c4 * 4);
            short* da = As + row * LDA + c4 * 4;
            short* db = Bs + row * LDA + c4 * 4;
            da[0] = f2bf(va.x); da[1] = f2bf(va.y); da[2] = f2bf(va.z); da[3] = f2bf(va.w);
            db[0] = f2bf(vb.x); db[1] = f2bf(vb.y); db[2] = f2bf(vb.z); db[3] = f2bf(vb.w);
        }
        __syncthreads();
        // fragments: A[m=lr][k=quad*8+j], B[n=lr][k=quad*8+j] (gemm_bt)
        bf16x8 af[4], bfr[4];
        #pragma unroll
        for (int mi = 0; mi < 4; mi++)
            af[mi] = *(const bf16x8*)(As + (wm * 64 + mi * 16 + lr) * LDA + quad * 8);
        #pragma unroll
        for (int ni = 0; ni < 4; ni++)
            bfr[ni] = *(const bf16x8*)(Bs + (wn * 64 + ni * 16 + lr) * LDA + quad * 8);
        #pragma unroll
        for (int mi = 0; mi < 4; mi++)
            #pragma unroll
            for (int ni = 0; ni < 4; ni++)
                acc[mi][ni] = __builtin_amdgcn_mfma_f32_16x16x32_bf16(
                    af[mi], bfr[ni], acc[mi][ni], 0, 0, 0);
    }

    // epilogue: e_partial[m] = sum_h tanh(acc + t[b,h]) * V[h]
    // C/D layout: col = lane&15, row = quad*4 + reg  [verified m89/m91]
    const float* trow = t + b * 512;
    float th[4], vv[4];
    #pragma unroll
    for (int ni = 0; ni < 4; ni++) {
        const int h = h0 + wn * 64 + ni * 16 + lr;
        th[ni] = trow[h];
        vv[ni] = V[h];
    }
    #pragma unroll
    for (int mi = 0; mi < 4; mi++) {
        #pragma unroll
        for (int r = 0; r < 4; r++) {
            float es = 0.f;
            #pragma unroll
            for (int ni = 0; ni < 4; ni++) {
                float val = acc[mi][ni][r] + th[ni];
                es += fast_tanh(val) * vv[ni];
            }
            // reduce across the 16 cols (lanes lr=0..15 within each quad group)
            es += __shfl_xor(es, 1);
            es += __shfl_xor(es, 2);
            es += __shfl_xor(es, 4);
            es += __shfl_xor(es, 8);
            if (lr == 0) {
                const long m = m0 + wm * 64 + mi * 16 + quad * 4 + r;
                atomicAdd(&e[m], es);
            }
        }
    }
}

// ---- per-b softmax stats: max, sum(exp(e-max)) ----
__global__ void stats_kernel(const float* __restrict__ e, float* __restrict__ stats) {
    const int b = blockIdx.x, tid = threadIdx.x;   // 256
    __shared__ float red[256];
    float mx = -1e30f;
    for (int s = tid; s < 4096; s += 256) mx = fmaxf(mx, e[b * 4096 + s]);
    red[tid] = mx; __syncthreads();
    for (int st = 128; st > 0; st >>= 1) {
        if (tid < st) red[tid] = fmaxf(red[tid], red[tid + st]);
        __syncthreads();
    }
    mx = red[0]; __syncthreads();
    float sm = 0.f;
    for (int s = tid; s < 4096; s += 256)
        sm += exp2f((e[b * 4096 + s] - mx) * 1.4426950408889634f);
    red[tid] = sm; __syncthreads();
    for (int st = 128; st > 0; st >>= 1) {
        if (tid < st) red[tid] += red[tid + st];
        __syncthreads();
    }
    if (tid == 0) { stats[b * 2] = mx; stats[b * 2 + 1] = red[0]; }
}

// ---- att = softmax(e)*mask (write), ctx partial = sum_s att*src -> atomicAdd ----
__global__ __launch_bounds__(256)
void ctx_kernel(const float* __restrict__ e, const float* __restrict__ stats,
                const float* __restrict__ mask, const float* __restrict__ src,
                float* __restrict__ att, float* __restrict__ outh) {
    const int b = blockIdx.y;
    const int s0 = blockIdx.x * 256;
    const int tid = threadIdx.x;
    __shared__ float ash[256];
    __shared__ float4 part[128];

    const float mx = stats[b * 2];
    const float inv = 1.0f / stats[b * 2 + 1];
    const int s = s0 + tid;
    float a = exp2f((e[b * 4096 + s] - mx) * 1.4426950408889634f) * inv
              * mask[b * 4096 + s];
    att[(long)b * 4096 + s] = a;
    ash[tid] = a;
    __syncthreads();

    const int half = tid >> 7, d4 = tid & 127;
    float4 acc = {0.f, 0.f, 0.f, 0.f};
    const float4* s4 = (const float4*)(src + ((long)b * 4096 + s0) * 512);
    for (int i = half; i < 256; i += 2) {          // coalesced: 128 lanes = one row
        float4 v = s4[(long)i * 128 + d4];
        float w = ash[i];
        acc.x += w * v.x; acc.y += w * v.y; acc.z += w * v.z; acc.w += w * v.w;
    }
    if (half) part[d4] = acc;
    __syncthreads();
    if (!half) {
        float4 p = part[d4];
        acc.x += p.x; acc.y += p.y; acc.z += p.z; acc.w += p.w;
        float* o = outh + b * 512 + d4 * 4;
        atomicAdd(o + 0, acc.x); atomicAdd(o + 1, acc.y);
        atomicAdd(o + 2, acc.z); atomicAdd(o + 3, acc.w);
    }
}

extern "C" void kernel_launch(void* const* d_in, const int* in_sizes, int n_in,
                              void* d_out, int out_size, void* d_ws, size_t ws_size,
                              hipStream_t stream) {
    const float* targ = (const float*)d_in[0];     // (32,512)
    const float* src  = (const float*)d_in[1];     // (32,4096,512)
    const float* mask = (const float*)d_in[2];     // (32,4096)
    const float* W    = (const float*)d_in[3];     // (512,1024)
    const float* V    = (const float*)d_in[4];     // (512)

    float* att  = (float*)d_out;                   // 131072
    float* outh = (float*)d_out + 131072;          // 16384

    float* e  = (float*)d_ws;                      // 131072 floats
    float* t  = e + 131072;                        // 16384 floats
    float* st = t + 16384;                         // 64 floats

    // e must start at zero (ws is poisoned 0xAA each launch)
    hipMemsetAsync(e, 0, 131072 * sizeof(float), stream);
    // hidden_output starts as hidden_targ; ctx atomicAdds on top
    hipMemcpyAsync(outh, targ, 16384 * sizeof(float), hipMemcpyDeviceToDevice, stream);

    t_kernel<<<32, 256, 0, stream>>>(targ, W, t);
    gemm_e_kernel<<<dim3(4, 1024), 256, 0, stream>>>(src, W, t, V, e);
    stats_kernel<<<32, 256, 0, stream>>>(e, st);
    ctx_kernel<<<dim3(16, 32), 256, 0, stream>>>(e, st, mask, src, att, outh);
}

// Round 2
// 503.827 us; speedup vs baseline: 1.4540x; 1.4540x over previous
//
#include <hip/hip_runtime.h>
#include <hip/hip_bf16.h>

// Problem: B=32, S=4096, D=512.
// out = [att_weights (32,4096) fp32 | hidden_output (32,512) fp32]

typedef __attribute__((ext_vector_type(8))) short bf16x8;
typedef __attribute__((ext_vector_type(4))) float f32x4;

#define BM 128
#define BN 128
#define BKK 32
#define LDA 40   // A LDS row: 32 bf16 + 8 pad (80 B, 16B-aligned rows)

static __device__ __forceinline__ unsigned pack2(float a, float b) {
    // RNE fp32->bf16, two at a time, packed into one dword
    unsigned ua = __float_as_uint(a), ub = __float_as_uint(b);
    unsigned ra = (ua + 0x7fffu + ((ua >> 16) & 1u)) >> 16;
    unsigned rb = (ub + 0x7fffu + ((ub >> 16) & 1u)) & 0xffff0000u;
    return ra | rb;
}

static __device__ __forceinline__ void async_load16(const void* g, void* l) {
    __builtin_amdgcn_global_load_lds(
        (const __attribute__((address_space(1))) void*)g,
        (__attribute__((address_space(3))) void*)l, 16, 0, 0);
}

static __device__ __forceinline__ float fast_tanh(float x) {
    float ex = exp2f(x * 2.8853900817779268f);
    return 1.0f - 2.0f / (ex + 1.0f);
}

// ---- pre-convert Ws (W[:,512:]) to bf16, tile-contiguous + bank-swizzled ----
// 64 tiles (hx in [0,4), kt in [0,16)), each 128 rows x 32 k = 512 units of 16B.
// unit position p = r*4 + u'; stored data unit u = u' ^ ((r>>1)&3).
__global__ void wconv_kernel(const float* __restrict__ W, short* __restrict__ wbf) {
    const int gid = blockIdx.x * 256 + threadIdx.x;       // [0, 32768)
    const int tile = gid >> 9, p = gid & 511;
    const int hx = tile >> 4, ktile = tile & 15;
    const int r = p >> 2, up = p & 3;
    const int u = up ^ ((r >> 1) & 3);
    const float* s = W + (long)(hx * 128 + r) * 1024 + 512 + ktile * 32 + u * 8;
    float4 v0 = *(const float4*)(s);
    float4 v1 = *(const float4*)(s + 4);
    uint4 pk;
    pk.x = pack2(v0.x, v0.y); pk.y = pack2(v0.z, v0.w);
    pk.z = pack2(v1.x, v1.y); pk.w = pack2(v1.z, v1.w);
    ((uint4*)wbf)[gid] = pk;
}

// ---- t[b,h] = sum_d targ[b,d] * W[h, d] ----
__global__ void t_kernel(const float* __restrict__ targ,
                         const float* __restrict__ W,
                         float* __restrict__ t) {
    __shared__ float tg[512];
    const int b = blockIdx.x >> 2;
    const int hbase = (blockIdx.x & 3) * 128;
    const int tid = threadIdx.x;            // 256
    tg[tid]       = targ[b * 512 + tid];
    tg[tid + 256] = targ[b * 512 + tid + 256];
    __syncthreads();
    const int lane = tid & 63, wave = tid >> 6;
    for (int h = hbase + wave; h < hbase + 128; h += 4) {
        const float* wr = W + (long)h * 1024;
        float s = 0.f;
        #pragma unroll
        for (int i = 0; i < 2; i++) {
            const int d = lane * 4 + i * 256;
            float4 wv = *(const float4*)(wr + d);
            s += wv.x * tg[d] + wv.y * tg[d + 1] + wv.z * tg[d + 2] + wv.w * tg[d + 3];
        }
        s += __shfl_xor(s, 1);  s += __shfl_xor(s, 2);  s += __shfl_xor(s, 4);
        s += __shfl_xor(s, 8);  s += __shfl_xor(s, 16); s += __shfl_xor(s, 32);
        if (lane == 0) t[b * 512 + h] = s;
    }
}

// ---- e[m] += sum_h tanh(src@Ws^T + t)[m,h] * V[h] ----
// grid 4096 linear; swizzled so 4 h-blocks of one m-strip share an XCD.
__global__ __launch_bounds__(256, 2)
void gemm_e_kernel(const float* __restrict__ src,
                   const short* __restrict__ wbf,
                   const float* __restrict__ t,
                   const float* __restrict__ V,
                   float* __restrict__ e) {
    __shared__ __align__(16) short As[BM * LDA];   // padded, manual stores
    __shared__ __align__(16) short Bs[BN * BKK];   // unpadded, global_load_lds

    const int tid = threadIdx.x;
    const int L = blockIdx.x;
    const int mt = (L >> 5) * 8 + (L & 7);         // [0,1024)
    const int hx = (L >> 3) & 3;                   // [0,4)
    const long m0 = (long)mt * BM;
    const int b = (int)(m0 >> 12);

    const int lane = tid & 63;
    const int wave = tid >> 6;
    const int wm = wave & 1, wn = wave >> 1;
    const int lr = lane & 15, quad = lane >> 4;

    f32x4 acc[4][4];
    #pragma unroll
    for (int i = 0; i < 4; i++)
        #pragma unroll
        for (int j = 0; j < 4; j++)
            acc[i][j] = (f32x4){0.f, 0.f, 0.f, 0.f};

    const int arow = tid >> 1, ah = (tid & 1) * 16;   // A: one half-row per thread

    for (int kt = 0; kt < 512; kt += BKK) {
        __syncthreads();
        // B tile: 8KB contiguous, pre-swizzled in global -> async direct to LDS
        const short* chunk = wbf + (long)(hx * 16 + (kt >> 5)) * 4096;
        async_load16(chunk + tid * 8, Bs + tid * 8);
        async_load16(chunk + 2048 + tid * 8, Bs + 2048 + tid * 8);
        // A tile: fp32 load + packed bf16 convert + 2x ds_write_b128
        const float* ap = src + (m0 + arow) * 512 + kt + ah;
        float4 v0 = *(const float4*)(ap);
        float4 v1 = *(const float4*)(ap + 4);
        float4 v2 = *(const float4*)(ap + 8);
        float4 v3 = *(const float4*)(ap + 12);
        uint4 pA, pB;
        pA.x = pack2(v0.x, v0.y); pA.y = pack2(v0.z, v0.w);
        pA.z = pack2(v1.x, v1.y); pA.w = pack2(v1.z, v1.w);
        pB.x = pack2(v2.x, v2.y); pB.y = pack2(v2.z, v2.w);
        pB.z = pack2(v3.x, v3.y); pB.w = pack2(v3.z, v3.w);
        *(uint4*)(As + arow * LDA + ah)     = pA;
        *(uint4*)(As + arow * LDA + ah + 8) = pB;
        __syncthreads();   // compiler drains vmcnt (covers global_load_lds)

        bf16x8 af[4], bfr[4];
        #pragma unroll
        for (int mi = 0; mi < 4; mi++)
            af[mi] = *(const bf16x8*)(As + (wm * 64 + mi * 16 + lr) * LDA + quad * 8);
        #pragma unroll
        for (int ni = 0; ni < 4; ni++) {
            const int row = wn * 64 + ni * 16 + lr;
            const int q = quad ^ ((row >> 1) & 3);
            bfr[ni] = *(const bf16x8*)(Bs + row * 32 + q * 8);
        }
        #pragma unroll
        for (int mi = 0; mi < 4; mi++)
            #pragma unroll
            for (int ni = 0; ni < 4; ni++)
                acc[mi][ni] = __builtin_amdgcn_mfma_f32_16x16x32_bf16(
                    af[mi], bfr[ni], acc[mi][ni], 0, 0, 0);
    }

    // epilogue: e_partial[m] = sum_h tanh(acc + t[b,h]) * V[h]
    // C/D layout: col = lane&15, row = quad*4 + reg
    const float* trow = t + b * 512;
    float th[4], vv[4];
    #pragma unroll
    for (int ni = 0; ni < 4; ni++) {
        const int h = hx * 128 + wn * 64 + ni * 16 + lr;
        th[ni] = trow[h];
        vv[ni] = V[h];
    }
    #pragma unroll
    for (int mi = 0; mi < 4; mi++) {
        #pragma unroll
        for (int r = 0; r < 4; r++) {
            float es = 0.f;
            #pragma unroll
            for (int ni = 0; ni < 4; ni++) {
                float val = acc[mi][ni][r] + th[ni];
                es += fast_tanh(val) * vv[ni];
            }
            es += __shfl_xor(es, 1);
            es += __shfl_xor(es, 2);
            es += __shfl_xor(es, 4);
            es += __shfl_xor(es, 8);
            if (lr == 0) {
                const long m = m0 + wm * 64 + mi * 16 + quad * 4 + r;
                atomicAdd(&e[m], es);
            }
        }
    }
}

// ---- per-b softmax stats ----
__global__ void stats_kernel(const float* __restrict__ e, float* __restrict__ stats) {
    const int b = blockIdx.x, tid = threadIdx.x;
    __shared__ float red[256];
    float mx = -1e30f;
    for (int s = tid; s < 4096; s += 256) mx = fmaxf(mx, e[b * 4096 + s]);
    red[tid] = mx; __syncthreads();
    for (int st = 128; st > 0; st >>= 1) {
        if (tid < st) red[tid] = fmaxf(red[tid], red[tid + st]);
        __syncthreads();
    }
    mx = red[0]; __syncthreads();
    float sm = 0.f;
    for (int s = tid; s < 4096; s += 256)
        sm += exp2f((e[b * 4096 + s] - mx) * 1.4426950408889634f);
    red[tid] = sm; __syncthreads();
    for (int st = 128; st > 0; st >>= 1) {
        if (tid < st) red[tid] += red[tid + st];
        __syncthreads();
    }
    if (tid == 0) { stats[b * 2] = mx; stats[b * 2 + 1] = red[0]; }
}

// ---- att write + ctx accumulate ----
__global__ __launch_bounds__(256)
void ctx_kernel(const float* __restrict__ e, const float* __restrict__ stats,
                const float* __restrict__ mask, const float* __restrict__ src,
                float* __restrict__ att, float* __restrict__ outh) {
    const int b = blockIdx.y;
    const int s0 = blockIdx.x * 256;
    const int tid = threadIdx.x;
    __shared__ float ash[256];
    __shared__ float4 part[128];

    const float mx = stats[b * 2];
    const float inv = 1.0f / stats[b * 2 + 1];
    const int s = s0 + tid;
    float a = exp2f((e[b * 4096 + s] - mx) * 1.4426950408889634f) * inv
              * mask[b * 4096 + s];
    att[(long)b * 4096 + s] = a;
    ash[tid] = a;
    __syncthreads();

    const int half = tid >> 7, d4 = tid & 127;
    float4 acc = {0.f, 0.f, 0.f, 0.f};
    const float4* s4 = (const float4*)(src + ((long)b * 4096 + s0) * 512);
    #pragma unroll 4
    for (int i = half; i < 256; i += 2) {
        float4 v = s4[(long)i * 128 + d4];
        float w = ash[i];
        acc.x += w * v.x; acc.y += w * v.y; acc.z += w * v.z; acc.w += w * v.w;
    }
    if (half) part[d4] = acc;
    __syncthreads();
    if (!half) {
        float4 p = part[d4];
        acc.x += p.x; acc.y += p.y; acc.z += p.z; acc.w += p.w;
        float* o = outh + b * 512 + d4 * 4;
        atomicAdd(o + 0, acc.x); atomicAdd(o + 1, acc.y);
        atomicAdd(o + 2, acc.z); atomicAdd(o + 3, acc.w);
    }
}

extern "C" void kernel_launch(void* const* d_in, const int* in_sizes, int n_in,
                              void* d_out, int out_size, void* d_ws, size_t ws_size,
                              hipStream_t stream) {
    const float* targ = (const float*)d_in[0];     // (32,512)
    const float* src  = (const float*)d_in[1];     // (32,4096,512)
    const float* mask = (const float*)d_in[2];     // (32,4096)
    const float* W    = (const float*)d_in[3];     // (512,1024)
    const float* V    = (const float*)d_in[4];     // (512)

    float* att  = (float*)d_out;
    float* outh = (float*)d_out + 131072;

    float* e  = (float*)d_ws;                      // 131072 floats
    float* t  = e + 131072;                        // 16384 floats
    float* st = t + 16384;                         // 64 floats
    short* wbf = (short*)((char*)d_ws + 590080);   // 262144 bf16 (512 KB), 16B aligned

    hipMemsetAsync(e, 0, 131072 * sizeof(float), stream);
    hipMemcpyAsync(outh, targ, 16384 * sizeof(float), hipMemcpyDeviceToDevice, stream);

    wconv_kernel<<<128, 256, 0, stream>>>(W, wbf);
    t_kernel<<<128, 256, 0, stream>>>(targ, W, t);
    gemm_e_kernel<<<4096, 256, 0, stream>>>(src, wbf, t, V, e);
    stats_kernel<<<32, 256, 0, stream>>>(e, st);
    ctx_kernel<<<dim3(16, 32), 256, 0, stream>>>(e, st, mask, src, att, outh);
}